// Round 2
// baseline (15051.869 us; speedup 1.0000x reference)
//
#include <hip/hip_runtime.h>
#include <math.h>

#define B_  64
#define N_  512
#define H_  1024
#define NH_ 8
#define HD_ 128
#define S_  24

// ---------------------------------------------------------------------------
// Precompute: W2[n][0..1023] = 0.5*Wqt[n][k];  W2[n][1024+k] = 0.5*(Wqt·Wout)[n][k]
// 256 blocks: 16x16 grid of 64x64 tiles. 256 threads, 4x4 acc.
// ---------------------------------------------------------------------------
__global__ __launch_bounds__(256) void wc_pre(
    const float* __restrict__ Wqt, const float* __restrict__ Wout,
    float* __restrict__ W2)
{
  __shared__ float As[16][68];   // [m][n] of Wqt tile (transposed stage)
  __shared__ float Bs[16][68];   // [m][k] of Wout tile
  const int tid = threadIdx.x;
  const int k0 = (blockIdx.x & 15) * 64;
  const int n0 = (blockIdx.x >> 4) * 64;
  const int tn = tid & 15, tm = tid >> 4;

  // copy half: W2[n][k] = 0.5*Wqt[n][k]
#pragma unroll
  for (int i = 0; i < 4; ++i) {
    int n = n0 + tm * 4 + i;
    float4 w = *(const float4*)(Wqt + (size_t)n * 1024 + k0 + tn * 4);
    *(float4*)(W2 + (size_t)n * 2048 + k0 + tn * 4) =
        make_float4(0.5f * w.x, 0.5f * w.y, 0.5f * w.z, 0.5f * w.w);
  }

  float acc[4][4];
#pragma unroll
  for (int i = 0; i < 4; ++i)
#pragma unroll
    for (int j = 0; j < 4; ++j) acc[i][j] = 0.f;

  for (int m0 = 0; m0 < 1024; m0 += 16) {
    {
      int nn = tid >> 2, mm = (tid & 3) * 4;
      float4 a = *(const float4*)(Wqt + (size_t)(n0 + nn) * 1024 + m0 + mm);
      As[mm + 0][nn] = a.x; As[mm + 1][nn] = a.y;
      As[mm + 2][nn] = a.z; As[mm + 3][nn] = a.w;
      int mr = tid >> 4, kc = (tid & 15) * 4;
      float4 b = *(const float4*)(Wout + (size_t)(m0 + mr) * 1024 + k0 + kc);
      *(float4*)(&Bs[mr][kc]) = b;
    }
    __syncthreads();
#pragma unroll
    for (int m = 0; m < 16; ++m) {
      float av[4], bv[4];
      *(float4*)av = *(const float4*)(&As[m][tm * 4]);
      *(float4*)bv = *(const float4*)(&Bs[m][tn * 4]);
#pragma unroll
      for (int i = 0; i < 4; ++i)
#pragma unroll
        for (int j = 0; j < 4; ++j)
          acc[i][j] = fmaf(av[i], bv[j], acc[i][j]);
    }
    __syncthreads();
  }
#pragma unroll
  for (int i = 0; i < 4; ++i) {
    int n = n0 + tm * 4 + i;
    *(float4*)(W2 + (size_t)n * 2048 + 1024 + k0 + tn * 4) =
        make_float4(0.5f * acc[i][0], 0.5f * acc[i][1],
                    0.5f * acc[i][2], 0.5f * acc[i][3]);
  }
}

// bc[n] = 0.5*dot(Wqt[n,:], bout) + bqt[n].  256 blocks x 256 thr, wave per n.
// Also zeroes the grid-barrier counter (ws is poisoned between iterations).
__global__ __launch_bounds__(256) void bc_pre(
    const float* __restrict__ Wqt, const float* __restrict__ bout,
    const float* __restrict__ bqt, float* __restrict__ bc,
    unsigned* __restrict__ bar)
{
  if (blockIdx.x == 0 && threadIdx.x == 0) bar[0] = 0u;
  int w = threadIdx.x >> 6, lane = threadIdx.x & 63;
  int n = blockIdx.x * 4 + w;
  const float* row = Wqt + (size_t)n * 1024;
  float s = 0.f;
#pragma unroll
  for (int c = 0; c < 4; ++c) {
    float4 a = *(const float4*)(row + lane * 16 + c * 4);
    float4 b = *(const float4*)(bout + lane * 16 + c * 4);
    s = fmaf(a.x, b.x, fmaf(a.y, b.y, fmaf(a.z, b.z, fmaf(a.w, b.w, s))));
  }
#pragma unroll
  for (int off = 32; off > 0; off >>= 1) s += __shfl_down(s, off, 64);
  if (lane == 0) bc[n] = 0.5f * s + bqt[n];
}

// ---------------------------------------------------------------------------
// Device-scope grid barrier: monotonic counter, one atomic per block.
// Co-residency: 256 blocks, 1 block/CU on 256 CUs (VGPR capped by
// __launch_bounds__(512,4) so >=2 blocks/CU would also fit).
// ---------------------------------------------------------------------------
__device__ __forceinline__ void gridbar(unsigned* bar, unsigned target)
{
  __syncthreads();
  if (threadIdx.x == 0) {
    __threadfence();   // release prior writes device-wide
    __hip_atomic_fetch_add(bar, 1u, __ATOMIC_ACQ_REL, __HIP_MEMORY_SCOPE_AGENT);
    while (__hip_atomic_load(bar, __ATOMIC_ACQUIRE, __HIP_MEMORY_SCOPE_AGENT) < target)
      __builtin_amdgcn_s_sleep(1);
    __threadfence();   // acquire others' writes
  }
  __syncthreads();
}

__device__ __forceinline__ float sigm(float x) { return 1.f / (1.f + expf(-x)); }

__device__ __forceinline__ void ins3(float v, int i,
    float& v0, int& i0, float& v1, int& i1, float& v2, int& i2)
{
  if (v > v0 || (v == v0 && i < i0)) {
    v2 = v1; i2 = i1; v1 = v0; i1 = i0; v0 = v; i0 = i;
  } else if (v > v1 || (v == v1 && i < i1)) {
    v2 = v1; i2 = i1; v1 = v; i1 = i;
  } else if (v > v2 || (v == v2 && i < i2)) {
    v2 = v; i2 = i;
  }
}

// 64m x 128n tile GEMM body, 512 threads, As/Bs staged (tid<256 stages A).
__device__ __forceinline__ void gemm_tile(
    const float* __restrict__ Arow, const float* __restrict__ Wrow,
    int KS, int N, int sp, int nb, float* __restrict__ P,
    float* __restrict__ As, float* __restrict__ Bs)
{
  const int tid = threadIdx.x;
  const int tn = tid & 31, tm = tid >> 5;
  const int lr = tid >> 2, lc = (tid & 3) * 4;
  float acc[4][4];
#pragma unroll
  for (int i = 0; i < 4; ++i)
#pragma unroll
    for (int j = 0; j < 4; ++j) acc[i][j] = 0.f;
  for (int k0 = 0; k0 < KS; k0 += 16) {
    float4 b4 = *(const float4*)(Wrow + k0);
    if (tid < 256) {
      float4 a4 = *(const float4*)(Arow + k0);
      As[(lc + 0) * 68 + lr] = a4.x; As[(lc + 1) * 68 + lr] = a4.y;
      As[(lc + 2) * 68 + lr] = a4.z; As[(lc + 3) * 68 + lr] = a4.w;
    }
    Bs[(lc + 0) * 132 + lr] = b4.x; Bs[(lc + 1) * 132 + lr] = b4.y;
    Bs[(lc + 2) * 132 + lr] = b4.z; Bs[(lc + 3) * 132 + lr] = b4.w;
    __syncthreads();
#pragma unroll
    for (int k = 0; k < 16; ++k) {
      float av[4], bv[4];
      *(float4*)av = *(const float4*)(As + k * 68 + tm * 4);
      *(float4*)bv = *(const float4*)(Bs + k * 132 + tn * 4);
#pragma unroll
      for (int i = 0; i < 4; ++i)
#pragma unroll
        for (int j = 0; j < 4; ++j)
          acc[i][j] = fmaf(av[i], bv[j], acc[i][j]);
    }
    __syncthreads();
  }
  float* Pb = P + (size_t)sp * 64 * N + nb * 128;
#pragma unroll
  for (int i = 0; i < 4; ++i)
    *(float4*)(Pb + (size_t)(tm * 4 + i) * N + tn * 4) =
        make_float4(acc[i][0], acc[i][1], acc[i][2], acc[i][3]);
}

struct DecParams {
  const float* enc; const float* h0; const float* c0; const float* x0;
  const float* W_ih; const float* b_ih; const float* W_hh; const float* b_hh;
  const float* Wqkv; const float* bqkv; const float* W2; const float* bc;
  float* P; float* hbuf; float* cbuf; float* ctx; float* Kc; float* Vc;
  float* qbuf; float* candv; int* candi; int* idxi; unsigned* bar;
  float* logits_out; float* idx_out;
};

// ---------------------------------------------------------------------------
// Persistent kernel: all 24 decoder steps, 8 grid-barriered phases per step.
// 256 blocks x 512 threads.
// ---------------------------------------------------------------------------
__global__ __launch_bounds__(512, 4) void decoder_all(DecParams p)
{
  __shared__ float smem[3200];          // 12.8 KB: gemm As(1088)+Bs(2112); attn 4x160
  float* As = smem;
  float* Bs = smem + 1088;
  const int bid = blockIdx.x;
  const int tid = threadIdx.x;
  const unsigned nblk = gridDim.x;
  unsigned gen = 0;

  for (int t = 0; t < S_; ++t) {
    // ---- A: gates GEMM  P[8][64][4096] = [x|h] @ [W_ih|W_hh]^T ----
    {
      const int nb = bid & 31, sp = bid >> 5;
      const int ks = sp * 512;
      const int lr = tid >> 2, lc = (tid & 3) * 4;
      const float* W; int ldW, koff; const float* A; int ldA; int gat;
      if (ks < 3072) { W = p.W_ih; ldW = 3072; koff = ks;
                       A = p.x0;  ldA = 3072; gat = (t > 0); }
      else           { W = p.W_hh; ldW = 1024; koff = ks - 3072;
                       A = (t == 0) ? p.h0 : p.hbuf; ldA = 1024; gat = 0; }
      const float* Wrow = W + (size_t)(nb * 128 + lr) * ldW + koff + lc;
      const float* Arow = nullptr;
      if (tid < 256) {
        if (gat) {
          int ei = p.idxi[lr * 3 + (koff >> 10)];
          Arow = p.enc + ((size_t)lr * 512 + ei) * 1024 + (koff & 1023) + lc;
        } else {
          Arow = A + (size_t)lr * ldA + koff + lc;
        }
      }
      gemm_tile(Arow, Wrow, 512, 4096, sp, nb, p.P, As, Bs);
    }
    ++gen; gridbar(p.bar, gen * nblk);

    // ---- B: LSTM reduce + pointwise -> hbuf, cbuf ----
    if (tid < 64) {
      const int item = bid * 64 + tid;             // 0..16383
      const int b = item >> 8, j4 = (item & 255) * 4;
      const float* cin = (t == 0) ? p.c0 : p.cbuf;
      float g[4][4];
#pragma unroll
      for (int c = 0; c < 4; ++c) {
        int n = c * 1024 + j4;
        float4 s = *(const float4*)(p.b_ih + n);
        float4 s2 = *(const float4*)(p.b_hh + n);
        s.x += s2.x; s.y += s2.y; s.z += s2.z; s.w += s2.w;
#pragma unroll
        for (int sp = 0; sp < 8; ++sp) {
          float4 v = *(const float4*)(p.P + ((size_t)sp * 64 + b) * 4096 + n);
          s.x += v.x; s.y += v.y; s.z += v.z; s.w += v.w;
        }
        g[c][0] = s.x; g[c][1] = s.y; g[c][2] = s.z; g[c][3] = s.w;
      }
      float4 cp = *(const float4*)(cin + b * 1024 + j4);
      float cv[4] = {cp.x, cp.y, cp.z, cp.w};
      float4 ho, co; float* hp = &ho.x; float* cpn = &co.x;
#pragma unroll
      for (int e = 0; e < 4; ++e) {
        float c = sigm(g[1][e]) * cv[e] + sigm(g[0][e]) * tanhf(g[2][e]);
        cpn[e] = c; hp[e] = sigm(g[3][e]) * tanhf(c);
      }
      *(float4*)(p.cbuf + b * 1024 + j4) = co;
      *(float4*)(p.hbuf + b * 1024 + j4) = ho;
    }
    ++gen; gridbar(p.bar, gen * nblk);

    // ---- C: qkv GEMM  P[8][64][3072] = h @ Wqkv^T ----
    if (bid < 192) {
      const int nb = bid >> 3, sp = bid & 7;
      const int koff = sp * 128;
      const int lr = tid >> 2, lc = (tid & 3) * 4;
      const float* Wrow = p.Wqkv + (size_t)(nb * 128 + lr) * 1024 + koff + lc;
      const float* Arow = (tid < 256)
          ? p.hbuf + (size_t)lr * 1024 + koff + lc : nullptr;
      gemm_tile(Arow, Wrow, 128, 3072, sp, nb, p.P, As, Bs);
    }
    ++gen; gridbar(p.bar, gen * nblk);

    // ---- D: attention (4 (b,h)-pairs per block, 128 thr each) ----
    if (bid < 128) {
      const int grp = tid >> 7;                    // 0..3
      const int pair = bid * 4 + grp;              // 0..511
      const int b = pair >> 3, h = pair & 7, d = tid & 127;
      float* qs = smem + grp * 160;
      float* sc = qs + 128;
      const float scale = 0.08838834764831845f;    // 1/sqrt(128)
      const float* Pb = p.P + (size_t)b * 3072 + h * 128 + d;
      float qv = p.bqkv[h * 128 + d];
      float kv = p.bqkv[1024 + h * 128 + d];
      float vv = p.bqkv[2048 + h * 128 + d];
#pragma unroll
      for (int sp = 0; sp < 8; ++sp) {
        const float* pp = Pb + (size_t)sp * 64 * 3072;
        qv += pp[0]; kv += pp[1024]; vv += pp[2048];
      }
      float* Kb = p.Kc + (size_t)(b * NH_ + h) * S_ * HD_;
      float* Vb = p.Vc + (size_t)(b * NH_ + h) * S_ * HD_;
      Kb[t * 128 + d] = kv;
      Vb[t * 128 + d] = vv;
      qs[d] = qv;
      __syncthreads();
      int w2 = d >> 6, lane = d & 63;
      for (int s = w2; s <= t; s += 2) {
        float pr = qs[lane] * Kb[s * 128 + lane] +
                   qs[lane + 64] * Kb[s * 128 + lane + 64];
#pragma unroll
        for (int off = 32; off > 0; off >>= 1) pr += __shfl_down(pr, off, 64);
        if (lane == 0) sc[s] = pr * scale;
      }
      __syncthreads();
      float m = -3.4e38f;
      for (int s = 0; s <= t; ++s) m = fmaxf(m, sc[s]);
      float den = 0.f;
      for (int s = 0; s <= t; ++s) den += expf(sc[s] - m);
      float acc = 0.f;
      for (int s = 0; s <= t; ++s) acc += expf(sc[s] - m) * Vb[s * 128 + d];
      p.ctx[(size_t)b * 1024 + h * 128 + d] = acc / den;
    }
    ++gen; gridbar(p.bar, gen * nblk);

    // ---- E: query GEMM  P[16][64][1024] = [h|ctx] @ W2^T ----
    if (bid < 128) {
      const int nb = bid & 7, sp = bid >> 3;
      const int lr = tid >> 2, lc = (tid & 3) * 4;
      const float* A; const float* W; int koff;
      if (sp < 8) { A = p.hbuf; W = p.W2;        koff = sp * 128; }
      else        { A = p.ctx;  W = p.W2 + 1024; koff = (sp - 8) * 128; }
      const float* Wrow = W + (size_t)(nb * 128 + lr) * 2048 + koff + lc;
      const float* Arow = (tid < 256)
          ? A + (size_t)lr * 1024 + koff + lc : nullptr;
      gemm_tile(Arow, Wrow, 128, 1024, sp, nb, p.P, As, Bs);
    }
    ++gen; gridbar(p.bar, gen * nblk);

    // ---- F: qt reduce -> qbuf[64][1024] ----
    if (tid < 64) {
      const int item = bid * 64 + tid;             // 0..16383
      const int b = item >> 8, j4 = (item & 255) * 4;
      float4 s = *(const float4*)(p.bc + j4);
#pragma unroll
      for (int sp = 0; sp < 16; ++sp) {
        float4 v = *(const float4*)(p.P + ((size_t)sp * 64 + b) * 1024 + j4);
        s.x += v.x; s.y += v.y; s.z += v.z; s.w += v.w;
      }
      *(float4*)(p.qbuf + (size_t)b * 1024 + j4) = s;
    }
    ++gen; gridbar(p.bar, gen * nblk);

    // ---- G: logits + per-chunk top3 (1 wave = 16 enc rows) ----
    {
      const int wave = tid >> 6, lane = tid & 63;
      const int lb = bid * 8 + wave;               // 0..2047
      const int b = lb >> 5, ch = lb & 31;
      const float* qb = p.qbuf + (size_t)b * 1024 + lane * 4;
      float4 q0 = *(const float4*)(qb);
      float4 q1 = *(const float4*)(qb + 256);
      float4 q2 = *(const float4*)(qb + 512);
      float4 q3 = *(const float4*)(qb + 768);
      const float* eb = p.enc + ((size_t)b * N_ + ch * 16) * 1024 + lane * 4;
      float v0 = -3.4e38f, v1 = -3.4e38f, v2 = -3.4e38f;
      int i0 = 0x7fffffff, i1 = 0x7fffffff, i2 = 0x7fffffff;
      float myout = 0.f;
      float* lo = p.logits_out + (size_t)t * B_ * N_ + (size_t)b * N_ + ch * 16;
#pragma unroll 4
      for (int r = 0; r < 16; ++r) {
        const float* e = eb + (size_t)r * 1024;
        float4 e0 = *(const float4*)(e);
        float4 e1 = *(const float4*)(e + 256);
        float4 e2 = *(const float4*)(e + 512);
        float4 e3 = *(const float4*)(e + 768);
        float s = 0.f;
        s = fmaf(q0.x, e0.x, s); s = fmaf(q0.y, e0.y, s);
        s = fmaf(q0.z, e0.z, s); s = fmaf(q0.w, e0.w, s);
        s = fmaf(q1.x, e1.x, s); s = fmaf(q1.y, e1.y, s);
        s = fmaf(q1.z, e1.z, s); s = fmaf(q1.w, e1.w, s);
        s = fmaf(q2.x, e2.x, s); s = fmaf(q2.y, e2.y, s);
        s = fmaf(q2.z, e2.z, s); s = fmaf(q2.w, e2.w, s);
        s = fmaf(q3.x, e3.x, s); s = fmaf(q3.y, e3.y, s);
        s = fmaf(q3.z, e3.z, s); s = fmaf(q3.w, e3.w, s);
#pragma unroll
        for (int off = 32; off > 0; off >>= 1) s += __shfl_xor(s, off, 64);
        if (lane == r) myout = s;
        ins3(s, ch * 16 + r, v0, i0, v1, i1, v2, i2);
      }
      if (lane < 16) lo[lane] = myout;
      if (lane == 0) {
        p.candv[lb * 3 + 0] = v0; p.candi[lb * 3 + 0] = i0;
        p.candv[lb * 3 + 1] = v1; p.candi[lb * 3 + 1] = i1;
        p.candv[lb * 3 + 2] = v2; p.candi[lb * 3 + 2] = i2;
      }
    }
    ++gen; gridbar(p.bar, gen * nblk);

    // ---- H: merge 32 chunks -> top3, sorted ascending ----
    if (bid == 0 && tid < 64) {
      const int b = tid;
      float v0 = -3.4e38f, v1 = -3.4e38f, v2 = -3.4e38f;
      int i0 = 0x7fffffff, i1 = 0x7fffffff, i2 = 0x7fffffff;
      for (int q = 0; q < 32; ++q) {
        int base = (b * 32 + q) * 3;
#pragma unroll
        for (int k = 0; k < 3; ++k)
          ins3(p.candv[base + k], p.candi[base + k], v0, i0, v1, i1, v2, i2);
      }
      int a = i0, bb = i1, c = i2, tw;
      if (a > bb) { tw = a; a = bb; bb = tw; }
      if (bb > c) { tw = bb; bb = c; c = tw; }
      if (a > bb) { tw = a; a = bb; bb = tw; }
      p.idxi[b * 3 + 0] = a; p.idxi[b * 3 + 1] = bb; p.idxi[b * 3 + 2] = c;
      float* io = p.idx_out + (size_t)t * B_ * 3 + b * 3;
      io[0] = (float)a; io[1] = (float)bb; io[2] = (float)c;
    }
    ++gen; gridbar(p.bar, gen * nblk);
  }
}

// ---------------------------------------------------------------------------
extern "C" void kernel_launch(void* const* d_in, const int* in_sizes, int n_in,
                              void* d_out, int out_size, void* d_ws, size_t ws_size,
                              hipStream_t stream)
{
  (void)in_sizes; (void)n_in; (void)out_size; (void)ws_size;
  const float* enc   = (const float*)d_in[0];
  const float* h0    = (const float*)d_in[1];
  const float* c0    = (const float*)d_in[2];
  const float* x0    = (const float*)d_in[4];
  const float* W_ih  = (const float*)d_in[6];
  const float* b_ih  = (const float*)d_in[7];
  const float* W_hh  = (const float*)d_in[8];
  const float* b_hh  = (const float*)d_in[9];
  const float* Wqkv  = (const float*)d_in[10];
  const float* bqkv  = (const float*)d_in[11];
  const float* Wout  = (const float*)d_in[12];
  const float* bout  = (const float*)d_in[13];
  const float* Wqt   = (const float*)d_in[14];
  const float* bqt   = (const float*)d_in[15];

  float* ws   = (float*)d_ws;
  float* P    = ws;                          // 8*64*4096 = 2.097M floats max
  float* W2   = P + 8 * 64 * 4096;           // 1024*2048
  float* bc   = W2 + 1024 * 2048;            // 1024
  float* hbuf = bc + 1024;                   // 64*1024
  float* cbuf = hbuf + 64 * 1024;
  float* ctx  = cbuf + 64 * 1024;
  float* Kc   = ctx + 64 * 1024;             // 64*8*24*128
  float* Vc   = Kc + 64 * NH_ * S_ * HD_;
  int*   idxi = (int*)(Vc + 64 * NH_ * S_ * HD_);  // 192
  unsigned* bar = (unsigned*)(idxi + 192);         // grid barrier counter

  // transient buffers carved from the unused upper half of P (query GEMM only
  // writes P[0 .. 16*64*1024); consumers run before the region is clobbered):
  float* qbuf  = P + 16 * 64 * 1024;         // 64*1024
  float* candv = qbuf + 64 * 1024;           // 2048*3
  int*   candi = (int*)(candv + 2048 * 3);   // 2048*3

  float* logits_out = (float*)d_out;                     // [S,B,N]
  float* idx_out    = logits_out + (size_t)S_ * B_ * N_; // [S,B,3] as float

  // once per launch: combined qt weights/bias (step-invariant) + bar reset
  wc_pre<<<dim3(256), dim3(256), 0, stream>>>(Wqt, Wout, W2);
  bc_pre<<<dim3(256), dim3(256), 0, stream>>>(Wqt, bout, bqt, bc, bar);

  DecParams prm;
  prm.enc = enc; prm.h0 = h0; prm.c0 = c0; prm.x0 = x0;
  prm.W_ih = W_ih; prm.b_ih = b_ih; prm.W_hh = W_hh; prm.b_hh = b_hh;
  prm.Wqkv = Wqkv; prm.bqkv = bqkv; prm.W2 = W2; prm.bc = bc;
  prm.P = P; prm.hbuf = hbuf; prm.cbuf = cbuf; prm.ctx = ctx;
  prm.Kc = Kc; prm.Vc = Vc; prm.qbuf = qbuf;
  prm.candv = candv; prm.candi = candi; prm.idxi = idxi; prm.bar = bar;
  prm.logits_out = logits_out; prm.idx_out = idx_out;

  decoder_all<<<dim3(256), dim3(512), 0, stream>>>(prm);
}

// Round 3
// 3741.549 us; speedup vs baseline: 4.0229x; 4.0229x over previous
//
#include <hip/hip_runtime.h>
#include <math.h>

#define B_  64
#define N_  512
#define H_  1024
#define NH_ 8
#define HD_ 128
#define S_  24

// ---------------------------------------------------------------------------
// Precompute: W2[n][0..1023] = 0.5*Wqt[n][k];  W2[n][1024+k] = 0.5*(Wqt·Wout)[n][k]
// 256 blocks: 16x16 grid of 64x64 tiles. 256 threads, 4x4 acc.
// ---------------------------------------------------------------------------
__global__ __launch_bounds__(256) void wc_pre(
    const float* __restrict__ Wqt, const float* __restrict__ Wout,
    float* __restrict__ W2)
{
  __shared__ float As[16][68];   // [m][n] of Wqt tile (transposed stage)
  __shared__ float Bs[16][68];   // [m][k] of Wout tile
  const int tid = threadIdx.x;
  const int k0 = (blockIdx.x & 15) * 64;
  const int n0 = (blockIdx.x >> 4) * 64;
  const int tn = tid & 15, tm = tid >> 4;

  // copy half: W2[n][k] = 0.5*Wqt[n][k]
#pragma unroll
  for (int i = 0; i < 4; ++i) {
    int n = n0 + tm * 4 + i;
    float4 w = *(const float4*)(Wqt + (size_t)n * 1024 + k0 + tn * 4);
    *(float4*)(W2 + (size_t)n * 2048 + k0 + tn * 4) =
        make_float4(0.5f * w.x, 0.5f * w.y, 0.5f * w.z, 0.5f * w.w);
  }

  float acc[4][4];
#pragma unroll
  for (int i = 0; i < 4; ++i)
#pragma unroll
    for (int j = 0; j < 4; ++j) acc[i][j] = 0.f;

  for (int m0 = 0; m0 < 1024; m0 += 16) {
    {
      int nn = tid >> 2, mm = (tid & 3) * 4;
      float4 a = *(const float4*)(Wqt + (size_t)(n0 + nn) * 1024 + m0 + mm);
      As[mm + 0][nn] = a.x; As[mm + 1][nn] = a.y;
      As[mm + 2][nn] = a.z; As[mm + 3][nn] = a.w;
      int mr = tid >> 4, kc = (tid & 15) * 4;
      float4 b = *(const float4*)(Wout + (size_t)(m0 + mr) * 1024 + k0 + kc);
      *(float4*)(&Bs[mr][kc]) = b;
    }
    __syncthreads();
#pragma unroll
    for (int m = 0; m < 16; ++m) {
      float av[4], bv[4];
      *(float4*)av = *(const float4*)(&As[m][tm * 4]);
      *(float4*)bv = *(const float4*)(&Bs[m][tn * 4]);
#pragma unroll
      for (int i = 0; i < 4; ++i)
#pragma unroll
        for (int j = 0; j < 4; ++j)
          acc[i][j] = fmaf(av[i], bv[j], acc[i][j]);
    }
    __syncthreads();
  }
#pragma unroll
  for (int i = 0; i < 4; ++i) {
    int n = n0 + tm * 4 + i;
    *(float4*)(W2 + (size_t)n * 2048 + 1024 + k0 + tn * 4) =
        make_float4(0.5f * acc[i][0], 0.5f * acc[i][1],
                    0.5f * acc[i][2], 0.5f * acc[i][3]);
  }
}

// bc[n] = 0.5*dot(Wqt[n,:], bout) + bqt[n].  256 blocks x 256 thr, wave per n.
__global__ __launch_bounds__(256) void bc_pre(
    const float* __restrict__ Wqt, const float* __restrict__ bout,
    const float* __restrict__ bqt, float* __restrict__ bc)
{
  int w = threadIdx.x >> 6, lane = threadIdx.x & 63;
  int n = blockIdx.x * 4 + w;
  const float* row = Wqt + (size_t)n * 1024;
  float s = 0.f;
#pragma unroll
  for (int c = 0; c < 4; ++c) {
    float4 a = *(const float4*)(row + lane * 16 + c * 4);
    float4 b = *(const float4*)(bout + lane * 16 + c * 4);
    s = fmaf(a.x, b.x, fmaf(a.y, b.y, fmaf(a.z, b.z, fmaf(a.w, b.w, s))));
  }
#pragma unroll
  for (int off = 32; off > 0; off >>= 1) s += __shfl_down(s, off, 64);
  if (lane == 0) bc[n] = 0.5f * s + bqt[n];
}

// ---------------------------------------------------------------------------
// Split-K GEMM: P[sp][64][N] = A[64,K-slice] @ W[N,K-slice]^T
// Two K-segments with independent (A, ldA, W, ldW); koff = ks or ks-K0.
// Tile 64m x 128n, 512 threads, KS per split. Optional seg0 A-gather:
// A row b = enc[b*512 + idxi[b*3 + (koff>>10)]] (x = top3-gathered enc rows).
// ---------------------------------------------------------------------------
__global__ __launch_bounds__(512, 2) void gemm5(
    const float* __restrict__ A0, int ldA0, const float* __restrict__ W0, int ldW0,
    int K0,
    const float* __restrict__ A1, int ldA1, const float* __restrict__ W1, int ldW1,
    const float* __restrict__ enc, const int* __restrict__ idxi, int gather,
    float* __restrict__ P, int N, int KS)
{
  __shared__ float As[16 * 68];
  __shared__ float Bs[16 * 132];
  const int tid = threadIdx.x;
  const int nb = blockIdx.x, sp = blockIdx.y;
  const int ks = sp * KS;

  const float* A; const float* W; int ldA, ldW, koff; int seg0;
  if (ks < K0) { A = A0; W = W0; ldA = ldA0; ldW = ldW0; koff = ks; seg0 = 1; }
  else { A = A1; W = W1; ldA = ldA1; ldW = ldW1; koff = ks - K0; seg0 = 0; }

  const int tn = tid & 31, tm = tid >> 5;
  const int lr = tid >> 2, lc = (tid & 3) * 4;

  float acc[4][4];
#pragma unroll
  for (int i = 0; i < 4; ++i)
#pragma unroll
    for (int j = 0; j < 4; ++j) acc[i][j] = 0.f;

  const float* Wrow = W + (size_t)(nb * 128 + lr) * ldW + koff + lc;
  const float* Arow = nullptr;
  if (tid < 256) {
    if (seg0 && gather) {
      int ei = idxi[lr * 3 + (koff >> 10)];
      Arow = enc + ((size_t)lr * 512 + ei) * 1024 + (koff & 1023) + lc;
    } else {
      Arow = A + (size_t)lr * ldA + koff + lc;
    }
  }

  for (int k0 = 0; k0 < KS; k0 += 16) {
    float4 b4 = *(const float4*)(Wrow + k0);
    if (tid < 256) {
      float4 a4 = *(const float4*)(Arow + k0);
      As[(lc + 0) * 68 + lr] = a4.x; As[(lc + 1) * 68 + lr] = a4.y;
      As[(lc + 2) * 68 + lr] = a4.z; As[(lc + 3) * 68 + lr] = a4.w;
    }
    Bs[(lc + 0) * 132 + lr] = b4.x; Bs[(lc + 1) * 132 + lr] = b4.y;
    Bs[(lc + 2) * 132 + lr] = b4.z; Bs[(lc + 3) * 132 + lr] = b4.w;
    __syncthreads();
#pragma unroll
    for (int k = 0; k < 16; ++k) {
      float av[4], bv[4];
      *(float4*)av = *(const float4*)(As + k * 68 + tm * 4);
      *(float4*)bv = *(const float4*)(Bs + k * 132 + tn * 4);
#pragma unroll
      for (int i = 0; i < 4; ++i)
#pragma unroll
        for (int j = 0; j < 4; ++j)
          acc[i][j] = fmaf(av[i], bv[j], acc[i][j]);
    }
    __syncthreads();
  }
  float* Pb = P + (size_t)sp * 64 * N + nb * 128;
#pragma unroll
  for (int i = 0; i < 4; ++i)
    *(float4*)(Pb + (size_t)(tm * 4 + i) * N + tn * 4) =
        make_float4(acc[i][0], acc[i][1], acc[i][2], acc[i][3]);
}

// ---------------------------------------------------------------------------
// LSTM: reduce 8 gate partials + biases, pointwise -> h', c'.  float4 wide.
// ---------------------------------------------------------------------------
__device__ __forceinline__ float sigm(float x) { return 1.f / (1.f + expf(-x)); }

__global__ __launch_bounds__(256) void lstm_red(
    const float* __restrict__ P, const float* __restrict__ b_ih,
    const float* __restrict__ b_hh, const float* __restrict__ c_in,
    float* __restrict__ h_out, float* __restrict__ c_out)
{
  int idx = blockIdx.x * 256 + threadIdx.x;   // 0..16383
  int b = idx >> 8, j4 = (idx & 255) * 4;
  float g[4][4];
#pragma unroll
  for (int c = 0; c < 4; ++c) {
    int n = c * 1024 + j4;
    float4 s = *(const float4*)(b_ih + n);
    float4 s2 = *(const float4*)(b_hh + n);
    s.x += s2.x; s.y += s2.y; s.z += s2.z; s.w += s2.w;
#pragma unroll
    for (int sp = 0; sp < 8; ++sp) {
      float4 v = *(const float4*)(P + ((size_t)sp * 64 + b) * 4096 + n);
      s.x += v.x; s.y += v.y; s.z += v.z; s.w += v.w;
    }
    g[c][0] = s.x; g[c][1] = s.y; g[c][2] = s.z; g[c][3] = s.w;
  }
  float4 cp = *(const float4*)(c_in + b * 1024 + j4);
  float cv[4] = {cp.x, cp.y, cp.z, cp.w};
  float4 ho, co;
  float* hp = &ho.x; float* cpn = &co.x;
#pragma unroll
  for (int e = 0; e < 4; ++e) {
    float c = sigm(g[1][e]) * cv[e] + sigm(g[0][e]) * tanhf(g[2][e]);
    cpn[e] = c;
    hp[e] = sigm(g[3][e]) * tanhf(c);
  }
  *(float4*)(c_out + b * 1024 + j4) = co;
  *(float4*)(h_out + b * 1024 + j4) = ho;
}

// ---------------------------------------------------------------------------
// Attention with fused qkv-partial reduce. 512 blocks (b,h) x 128 threads.
// ---------------------------------------------------------------------------
__global__ __launch_bounds__(128) void attn_fused(
    const float* __restrict__ P, const float* __restrict__ bqkv,
    float* __restrict__ Kc, float* __restrict__ Vc,
    float* __restrict__ ctx, int t)
{
  const float scale = 0.08838834764831845f;  // 1/sqrt(128)
  int bh = blockIdx.x;
  int b = bh >> 3, h = bh & 7;
  int d = threadIdx.x;
  __shared__ float qs[128];
  __shared__ float sc[S_];

  const float* Pb = P + (size_t)b * 3072 + h * 128 + d;
  float qv = bqkv[h * 128 + d];
  float kv = bqkv[1024 + h * 128 + d];
  float vv = bqkv[2048 + h * 128 + d];
#pragma unroll
  for (int sp = 0; sp < 8; ++sp) {
    const float* pp = Pb + (size_t)sp * 64 * 3072;
    qv += pp[0]; kv += pp[1024]; vv += pp[2048];
  }
  float* Kb = Kc + (size_t)(b * NH_ + h) * S_ * HD_;
  float* Vb = Vc + (size_t)(b * NH_ + h) * S_ * HD_;
  Kb[t * 128 + d] = kv;
  Vb[t * 128 + d] = vv;
  qs[d] = qv;
  __syncthreads();

  int wave = d >> 6, lane = d & 63;
  for (int s = wave; s <= t; s += 2) {
    float pr = qs[lane] * Kb[s * 128 + lane] + qs[lane + 64] * Kb[s * 128 + lane + 64];
#pragma unroll
    for (int off = 32; off > 0; off >>= 1) pr += __shfl_down(pr, off, 64);
    if (lane == 0) sc[s] = pr * scale;
  }
  __syncthreads();

  float m = -3.4e38f;
  for (int s = 0; s <= t; ++s) m = fmaxf(m, sc[s]);
  float den = 0.f;
  for (int s = 0; s <= t; ++s) den += expf(sc[s] - m);
  float acc = 0.f;
  for (int s = 0; s <= t; ++s) acc += expf(sc[s] - m) * Vb[s * 128 + d];
  ctx[(size_t)b * 1024 + h * 128 + d] = acc / den;
}

// ---------------------------------------------------------------------------
__device__ __forceinline__ void ins3(float v, int i,
    float& v0, int& i0, float& v1, int& i1, float& v2, int& i2)
{
  if (v > v0 || (v == v0 && i < i0)) {
    v2 = v1; i2 = i1; v1 = v0; i1 = i0; v0 = v; i0 = i;
  } else if (v > v1 || (v == v1 && i < i1)) {
    v2 = v1; i2 = i1; v1 = v; i1 = i;
  } else if (v > v2 || (v == v2 && i < i2)) {
    v2 = v; i2 = i;
  }
}

// ---------------------------------------------------------------------------
// logits3: fused qt-reduce + wide logits + per-block top3.
// 512 blocks (b, 64-row chunk) x 512 thr.  Stage q[b] (reduce 16 split-K
// partials + bias) into LDS, then each of 8 waves computes 8 rows with
// float4 enc loads (1 KB/wave-instr), butterfly-reduced so all lanes hold
// the sum; per-wave top3 in registers, merged to one candidate triple.
// ---------------------------------------------------------------------------
__global__ __launch_bounds__(512) void logits3(
    const float* __restrict__ P, const float* __restrict__ bc,
    const float* __restrict__ enc, float* __restrict__ out,
    float* __restrict__ candv, int* __restrict__ candi)
{
  __shared__ float qs[1024];
  __shared__ float cv[24];
  __shared__ int   ci[24];
  const int tid = threadIdx.x;
  const int b = blockIdx.x >> 3, ng = blockIdx.x & 7;

  // stage q[b][0..1023] with fused split-K reduce (+bc)
  if (tid < 256) {
    const int j4 = tid * 4;
    float4 s = *(const float4*)(bc + j4);
#pragma unroll
    for (int sp = 0; sp < 16; ++sp) {
      float4 v = *(const float4*)(P + ((size_t)sp * 64 + b) * 1024 + j4);
      s.x += v.x; s.y += v.y; s.z += v.z; s.w += v.w;
    }
    *(float4*)(qs + j4) = s;
  }
  __syncthreads();

  const int wave = tid >> 6, lane = tid & 63;
  float4 q0 = *(const float4*)(qs + lane * 4);
  float4 q1 = *(const float4*)(qs + 256 + lane * 4);
  float4 q2 = *(const float4*)(qs + 512 + lane * 4);
  float4 q3 = *(const float4*)(qs + 768 + lane * 4);

  const int row0 = ng * 64 + wave * 8;            // 8 rows per wave
  const float* eb = enc + ((size_t)b * N_ + row0) * 1024 + lane * 4;
  float* lo = out + (size_t)b * N_ + row0;
  float v0 = -3.4e38f, v1 = -3.4e38f, v2 = -3.4e38f;
  int i0 = 0x7fffffff, i1 = 0x7fffffff, i2 = 0x7fffffff;
  float myout = 0.f;
#pragma unroll 4
  for (int r = 0; r < 8; ++r) {
    const float* e = eb + (size_t)r * 1024;
    float4 e0 = *(const float4*)(e);
    float4 e1 = *(const float4*)(e + 256);
    float4 e2 = *(const float4*)(e + 512);
    float4 e3 = *(const float4*)(e + 768);
    float s = 0.f;
    s = fmaf(q0.x, e0.x, s); s = fmaf(q0.y, e0.y, s);
    s = fmaf(q0.z, e0.z, s); s = fmaf(q0.w, e0.w, s);
    s = fmaf(q1.x, e1.x, s); s = fmaf(q1.y, e1.y, s);
    s = fmaf(q1.z, e1.z, s); s = fmaf(q1.w, e1.w, s);
    s = fmaf(q2.x, e2.x, s); s = fmaf(q2.y, e2.y, s);
    s = fmaf(q2.z, e2.z, s); s = fmaf(q2.w, e2.w, s);
    s = fmaf(q3.x, e3.x, s); s = fmaf(q3.y, e3.y, s);
    s = fmaf(q3.z, e3.z, s); s = fmaf(q3.w, e3.w, s);
#pragma unroll
    for (int off = 32; off > 0; off >>= 1) s += __shfl_xor(s, off, 64);
    if (lane == r) myout = s;
    ins3(s, row0 + r, v0, i0, v1, i1, v2, i2);
  }
  if (lane < 8) lo[lane] = myout;
  if (lane == 0) {
    cv[wave * 3 + 0] = v0; ci[wave * 3 + 0] = i0;
    cv[wave * 3 + 1] = v1; ci[wave * 3 + 1] = i1;
    cv[wave * 3 + 2] = v2; ci[wave * 3 + 2] = i2;
  }
  __syncthreads();
  if (tid == 0) {
    float w0 = -3.4e38f, w1 = -3.4e38f, w2 = -3.4e38f;
    int j0 = 0x7fffffff, j1 = 0x7fffffff, j2 = 0x7fffffff;
#pragma unroll
    for (int k = 0; k < 24; ++k)
      ins3(cv[k], ci[k], w0, j0, w1, j1, w2, j2);
    candv[blockIdx.x * 3 + 0] = w0; candi[blockIdx.x * 3 + 0] = j0;
    candv[blockIdx.x * 3 + 1] = w1; candi[blockIdx.x * 3 + 1] = j1;
    candv[blockIdx.x * 3 + 2] = w2; candi[blockIdx.x * 3 + 2] = j2;
  }
}

// ---------------------------------------------------------------------------
// Merge 8 chunks' candidates per b -> final top3, sorted ascending.
// 1 block x 64 threads; reads only ws, writes idxi (ws) + idx (d_out).
// ---------------------------------------------------------------------------
__global__ __launch_bounds__(64) void top3_merge(
    const float* __restrict__ candv, const int* __restrict__ candi,
    float* __restrict__ idx_out, int* __restrict__ idxi)
{
  int b = threadIdx.x;
  float v0 = -3.4e38f, v1 = -3.4e38f, v2 = -3.4e38f;
  int i0 = 0x7fffffff, i1 = 0x7fffffff, i2 = 0x7fffffff;
#pragma unroll
  for (int q = 0; q < 8; ++q) {
    int base = (b * 8 + q) * 3;
#pragma unroll
    for (int k = 0; k < 3; ++k)
      ins3(candv[base + k], candi[base + k], v0, i0, v1, i1, v2, i2);
  }
  int a = i0, bb = i1, c = i2, tw;
  if (a > bb) { tw = a; a = bb; bb = tw; }
  if (bb > c) { tw = bb; bb = c; c = tw; }
  if (a > bb) { tw = a; a = bb; bb = tw; }
  idxi[b * 3 + 0] = a; idxi[b * 3 + 1] = bb; idxi[b * 3 + 2] = c;
  idx_out[b * 3 + 0] = (float)a;
  idx_out[b * 3 + 1] = (float)bb;
  idx_out[b * 3 + 2] = (float)c;
}

// ---------------------------------------------------------------------------
extern "C" void kernel_launch(void* const* d_in, const int* in_sizes, int n_in,
                              void* d_out, int out_size, void* d_ws, size_t ws_size,
                              hipStream_t stream)
{
  (void)in_sizes; (void)n_in; (void)out_size; (void)ws_size;
  const float* enc   = (const float*)d_in[0];
  const float* h0    = (const float*)d_in[1];
  const float* c0    = (const float*)d_in[2];
  const float* x0    = (const float*)d_in[4];
  const float* W_ih  = (const float*)d_in[6];
  const float* b_ih  = (const float*)d_in[7];
  const float* W_hh  = (const float*)d_in[8];
  const float* b_hh  = (const float*)d_in[9];
  const float* Wqkv  = (const float*)d_in[10];
  const float* bqkv  = (const float*)d_in[11];
  const float* Wout  = (const float*)d_in[12];
  const float* bout  = (const float*)d_in[13];
  const float* Wqt   = (const float*)d_in[14];
  const float* bqt   = (const float*)d_in[15];

  float* ws   = (float*)d_ws;
  float* P    = ws;                          // 8*64*4096 = 2.097M floats max
  float* W2   = P + 8 * 64 * 4096;           // 1024*2048
  float* bc   = W2 + 1024 * 2048;            // 1024
  float* hbuf = bc + 1024;                   // 64*1024
  float* cbuf = hbuf + 64 * 1024;
  float* ctx  = cbuf + 64 * 1024;
  float* Kc   = ctx + 64 * 1024;             // 64*8*24*128
  float* Vc   = Kc + 64 * NH_ * S_ * HD_;
  float* candv = Vc + 64 * NH_ * S_ * HD_;   // 512*3
  int*   candi = (int*)(candv + 512 * 3);    // 512*3
  int*   idxi  = candi + 512 * 3;            // 192

  float* logits_out = (float*)d_out;                     // [S,B,N]
  float* idx_out    = logits_out + (size_t)S_ * B_ * N_; // [S,B,3] as float

  // once per launch: combined qt weights/bias (step-invariant)
  wc_pre<<<dim3(256), dim3(256), 0, stream>>>(Wqt, Wout, W2);
  bc_pre<<<dim3(256), dim3(256), 0, stream>>>(Wqt, bout, bqt, bc);

  for (int t = 0; t < S_; ++t) {
    const float* xin   = (t == 0) ? x0 : nullptr;   // t>0: gather from enc
    const float* hprev = (t == 0) ? h0 : hbuf;
    const float* cprev = (t == 0) ? c0 : cbuf;

    // gates = [x|h] @ [W_ih|W_hh]^T -> P[8][64][4096]
    gemm5<<<dim3(32, 8), dim3(512), 0, stream>>>(
        xin, 3072, W_ih, 3072, 3072,
        hprev, 1024, W_hh, 1024,
        enc, idxi, t > 0, P, 4096, 512);
    lstm_red<<<dim3(64), dim3(256), 0, stream>>>(P, b_ih, b_hh, cprev, hbuf, cbuf);

    // qkv = h @ Wqkv^T -> P[8][64][3072]
    gemm5<<<dim3(24, 8), dim3(512), 0, stream>>>(
        hbuf, 1024, Wqkv, 1024, 1024,
        hbuf, 1024, Wqkv, 1024,
        enc, idxi, 0, P, 3072, 128);
    attn_fused<<<dim3(512), dim3(128), 0, stream>>>(P, bqkv, Kc, Vc, ctx, t);

    // query = [h|ctx] @ W2^T (+bc at reduce) -> P[16][64][1024]
    gemm5<<<dim3(8, 16), dim3(512), 0, stream>>>(
        hbuf, 1024, W2, 2048, 1024,
        ctx, 1024, W2 + 1024, 2048,
        enc, idxi, 0, P, 1024, 128);
    logits3<<<dim3(512), dim3(512), 0, stream>>>(
        P, bc, enc, logits_out + (size_t)t * B_ * N_, candv, candi);
    top3_merge<<<dim3(1), dim3(64), 0, stream>>>(
        candv, candi, idx_out + (size_t)t * B_ * 3, idxi);
  }
}